// Round 13
// baseline (180.370 us; speedup 1.0000x reference)
//
#include <hip/hip_runtime.h>

// ActorCriticLoss fused kernel, v4: persistent grid-stride waves + prefetch.
//   out[0 .. B*T)        = sigmoid(logits)
//   out[B*T .. B*T+B*63) = lambda returns (reverse affine scan over T)
//
// Geometry (per iteration, same as v3): 16 lanes per row, 4 timesteps per
// lane, 4 rows per wave. lane = g*16+q; row = (wid + it*W)*4 + g.
// Recurrence C_t = a_t*C_{t+1} + b_t:
//   a_t = GAMMA*LAMDA*c_t ; b_t = r_t + GAMMA*(1-LAMDA)*c_t*v_{t+1}
// v4 change: 2048 persistent blocks (8/CU, full occupancy); each wave runs
// ~4 iterations, PREFETCHING the next iteration's 6 loads before processing
// the current one. One-shot waves paid one full memory round-trip per wave
// with ~35% duty cycle (rounds 4/7/9 all pinned at ~60us / 2.2 TB/s);
// steady-state prefetch keeps loads always in flight (m13 copy-ceiling style).

constexpr float GAMMA = 0.997f;
constexpr float LAMDA = 0.95f;
constexpr int T = 64;

struct Batch {
  float4 x, r, c, v;
  float v63, vnx;
};

__device__ __forceinline__ Batch load_batch(const float* __restrict__ logits,
                                            const float* __restrict__ rew,
                                            const float* __restrict__ con,
                                            const float* __restrict__ val,
                                            int row, int q) {
  const size_t rbase = (size_t)row * T;
  Batch b;
  b.x = ((const float4*)(logits + rbase))[q];
  b.r = ((const float4*)(rew    + rbase))[q];
  b.c = ((const float4*)(con    + rbase))[q];
  b.v = ((const float4*)(val    + rbase))[q];
  b.v63 = val[rbase + 63];                           // bootstrap (L1 hit)
  b.vnx = val[rbase + ((q < 15) ? 4 * q + 4 : 63)];  // v_{4q+4}   (L1 hit)
  return b;
}

__device__ __forceinline__ void process_store(const Batch& bt, int row, int q,
                                              int lane,
                                              float* __restrict__ out_sig,
                                              float* __restrict__ out_ret) {
  const size_t rbase = (size_t)row * T;
  constexpr float GL  = GAMMA * LAMDA;
  constexpr float G1L = GAMMA * (1.0f - LAMDA);

  // ---- sigmoid (aligned float4 store) ----
  float4 s;
  s.x = 1.0f / (1.0f + __expf(-bt.x.x));
  s.y = 1.0f / (1.0f + __expf(-bt.x.y));
  s.z = 1.0f / (1.0f + __expf(-bt.x.z));
  s.w = 1.0f / (1.0f + __expf(-bt.x.w));
  ((float4*)(out_sig + rbase))[q] = s;

  // ---- per-timestep affine maps (t = 4q+j) ----
  const float a0 = GL * bt.c.x, b0 = fmaf(G1L * bt.c.x, bt.v.y, bt.r.x);
  const float a1 = GL * bt.c.y, b1 = fmaf(G1L * bt.c.y, bt.v.z, bt.r.y);
  const float a2 = GL * bt.c.z, b2 = fmaf(G1L * bt.c.z, bt.v.w, bt.r.z);
  float a3, b3;
  if (q == 15) { a3 = 1.0f; b3 = 0.0f; }   // t=63: identity (seed pass)
  else         { a3 = GL * bt.c.w; b3 = fmaf(G1L * bt.c.w, bt.vnx, bt.r.w); }

  // ---- compose lane's block map: C_{4q} = A*C_{4q+4} + B ----
  float A = a3, Bb = b3;
  A = a2 * A; Bb = fmaf(a2, Bb, b2);
  A = a1 * A; Bb = fmaf(a1, Bb, b1);
  A = a0 * A; Bb = fmaf(a0, Bb, b0);

  // ---- 4-step suffix scan over the 16-lane group (8 bpermutes) ----
#pragma unroll
  for (int d = 1; d < 16; d <<= 1) {
    int src = lane + d; if (src > 63) src = 63;
    float Ain = __shfl(A, src);
    float Bin = __shfl(Bb, src);
    const bool ok = (q + d) < 16;        // identity beyond group end
    Ain = ok ? Ain : 1.0f;
    Bin = ok ? Bin : 0.0f;
    Bb = fmaf(A, Bin, Bb);               // self o src (src later in time)
    A  = A * Ain;
  }

  // ---- exclusive carry C_{4q+4} via +1 shift ----
  int srcx = lane + 1; if (srcx > 63) srcx = 63;
  float Aex = __shfl(A, srcx);
  float Bex = __shfl(Bb, srcx);
  const bool okx = q < 15;
  Aex = okx ? Aex : 1.0f;
  Bex = okx ? Bex : 0.0f;
  const float carry = fmaf(Aex, bt.v63, Bex);   // C_{4q+4}

  // ---- apply within lane, store 63 floats/row (write-combined scalars) ----
  const float c3 = fmaf(a3, carry, b3);
  const float c2 = fmaf(a2, c3, b2);
  const float c1 = fmaf(a1, c2, b1);
  const float c0 = fmaf(a0, c1, b0);
  float* orow = out_ret + (size_t)row * 63 + 4 * q;
  orow[0] = c0;
  orow[1] = c1;
  orow[2] = c2;
  if (q < 15) orow[3] = c3;                     // t=63 not an output
}

__global__ __launch_bounds__(256) void fused_k(const float* __restrict__ logits,
                                               const float* __restrict__ rew,
                                               const float* __restrict__ con,
                                               const float* __restrict__ val,
                                               float* __restrict__ out_sig,
                                               float* __restrict__ out_ret,
                                               int B) {
  const int gid  = blockIdx.x * blockDim.x + threadIdx.x;
  const int wid  = gid >> 6;
  const int lane = gid & 63;
  const int g    = lane >> 4;     // row within wave's 4-row batch
  const int q    = lane & 15;     // 4-timestep slot within row
  const int W    = (gridDim.x * blockDim.x) >> 6;   // total waves
  const int rowstep = W * 4;

  int row = wid * 4 + g;
  if (row >= B) return;

  // Software pipeline: prefetch next batch before processing current.
  Batch cur = load_batch(logits, rew, con, val, row, q);
  for (;;) {
    const int nrow = row + rowstep;
    const bool more = (nrow < B);   // wave-uniform (B % 4 == 0)
    Batch nxt;
    if (more) nxt = load_batch(logits, rew, con, val, nrow, q);
    process_store(cur, row, q, lane, out_sig, out_ret);
    if (!more) break;
    cur = nxt;                      // full-struct copy: stays in registers
    row = nrow;
  }
}

extern "C" void kernel_launch(void* const* d_in, const int* in_sizes, int n_in,
                              void* d_out, int out_size, void* d_ws, size_t ws_size,
                              hipStream_t stream) {
  const float* logits = (const float*)d_in[0];
  const float* rew    = (const float*)d_in[1];
  const float* con    = (const float*)d_in[2];
  const float* val    = (const float*)d_in[3];
  float* out = (float*)d_out;

  const int BT = in_sizes[0];   // B*T
  const int B  = BT / T;

  float* out_sig = out;                  // B*T floats
  float* out_ret = out + (size_t)BT;     // B*63 floats

  // Persistent grid: 2048 blocks = 8 blocks/CU on 256 CUs = 32 waves/CU.
  // 8192 waves x 4 rows -> 32768 rows per pass; B=131072 -> 4 iters/wave.
  int blocks = 2048;
  const int max_blocks = (B + 15) / 16;  // 16 rows per block per iteration
  if (blocks > max_blocks) blocks = max_blocks;
  fused_k<<<blocks, 256, 0, stream>>>(logits, rew, con, val, out_sig, out_ret, B);
}